// Round 4
// baseline (233.941 us; speedup 1.0000x reference)
//
#include <hip/hip_runtime.h>
#include <math.h>

typedef unsigned short u16;
typedef unsigned int   u32;

typedef __bf16 bf16x8 __attribute__((ext_vector_type(8)));
typedef float  f32x4  __attribute__((ext_vector_type(4)));

#define C_DIM 256
#define D_DIM 8192
#define QQ    32
#define HIDD  4096
#define Y0D   512
#define Y1D   2048
#define TWO_D 16384

__device__ __forceinline__ u16 f2bf(float f) {
    union { float f; u32 u; } v; v.f = f;
    u32 r = v.u + 0x7fffu + ((v.u >> 16) & 1u);   // RNE
    return (u16)(r >> 16);
}
__device__ __forceinline__ float geluf(float x) {
    return 0.5f * x * (1.0f + erff(x * 0.70710678118654752f));
}
// LDS swizzle: 16B chunk kg within a 64B row, XOR'd by row bits -> <=2-way conflicts
__device__ __forceinline__ int swz(int row, int kg) {
    return row * 64 + (((kg) ^ ((row >> 1) & 3)) << 4);
}
// fp32 LDS swizzle for the filter row buffer
__device__ __forceinline__ int xsw(int t) {
    int ch = t >> 2;
    return (((ch ^ ((ch >> 3) & 7))) << 2) | (t & 3);
}

// ---------------- weight network -> filter coefficients c[0..32], c[33]=sum ----
__global__ __launch_bounds__(256) void wcoef(const float* __restrict__ w1,
                                             const float* __restrict__ b1,
                                             const float* __restrict__ w2,
                                             const float* __restrict__ b2,
                                             float* __restrict__ c) {
    __shared__ float wl[65];
    int tid = threadIdx.x, lane = tid & 63, wv = tid >> 6;
    for (int li = wv; li < 65; li += 4) {
        float lag = (float)(li - 32);
        float h = lag * w1[lane] + b1[lane];
        h = geluf(h);
        float p = h * w2[lane];
        #pragma unroll
        for (int off = 32; off; off >>= 1) p += __shfl_xor(p, off);
        if (lane == 0) wl[li] = p + b2[0];
    }
    __syncthreads();
    if (tid <= 32) {
        float cv = (tid == 0) ? wl[32] / (float)D_DIM
                              : (wl[32 - tid] + wl[32 + tid]) / ((float)D_DIM - (float)tid);
        c[tid] = cv;
    }
    if (tid == 0) {
        float s = wl[32] / (float)D_DIM;
        for (int k = 1; k <= 32; ++k) s += (wl[32 - k] + wl[32 + k]) / ((float)D_DIM - (float)k);
        c[33] = s;
    }
}

// ---------------- per-row: mean -> mu[], Z = FIR(c, X-mu), bf16(X) into comb ----
__global__ __launch_bounds__(256) void filterk(const float* __restrict__ X,
                                               const float* __restrict__ c,
                                               float* __restrict__ mu_out,
                                               float* __restrict__ Z,
                                               u16* __restrict__ comb) {
    __shared__ float Xl[8240];
    __shared__ float cl[40];
    __shared__ float red[4];
    int i = blockIdx.x, tid = threadIdx.x;
    int lane = tid & 63, wv = tid >> 6;
    if (tid < 34) cl[tid] = c[tid];
    const float* row = X + (size_t)i * D_DIM;
    float s = 0.f;
    #pragma unroll
    for (int q = 0; q < 8; ++q) {
        int t = tid * 32 + q * 4;
        float4 v = *(const float4*)(row + t);
        s += v.x + v.y + v.z + v.w;
        *(float4*)(Xl + xsw(t)) = v;
    }
    #pragma unroll
    for (int off = 32; off; off >>= 1) s += __shfl_xor(s, off);
    if (lane == 0) red[wv] = s;
    __syncthreads();
    float mu = (red[0] + red[1] + red[2] + red[3]) * (1.f / (float)D_DIM);
    if (tid == 0) mu_out[i] = mu;
    if (tid < 10) {  // pad window with mu => (pad - mu) contributes 0 == truncation
        float4 mv = make_float4(mu, mu, mu, mu);
        *(float4*)(Xl + xsw(D_DIM + tid * 4)) = mv;
    }
    __syncthreads();
    float csum = cl[33];
    #pragma unroll
    for (int ch = 0; ch < 8; ++ch) {
        int t4 = tid * 32 + ch * 4;
        float w[40] __attribute__((aligned(16)));
        #pragma unroll
        for (int g = 0; g < 10; ++g)
            *(float4*)(w + g * 4) = *(const float4*)(Xl + xsw(t4 + g * 4));
        float za[4]; u16 cb[4];
        #pragma unroll
        for (int j = 0; j < 4; ++j) {
            float a = 0.f;
            #pragma unroll
            for (int k = 0; k < 33; ++k) a = fmaf(cl[k], w[j + k], a);
            za[j] = a - mu * csum;     // == sum_k c_k*(x[t+k]-mu) over valid k
            cb[j] = f2bf(w[j]);        // combined left half = bf16(X)
        }
        *(float4*)(Z + (size_t)i * D_DIM + t4) = make_float4(za[0], za[1], za[2], za[3]);
        uint2 pk; pk.x = (u32)cb[0] | ((u32)cb[1] << 16); pk.y = (u32)cb[2] | ((u32)cb[3] << 16);
        *(uint2*)(comb + (size_t)i * TWO_D + t4) = pk;
    }
}

// -------- cov partials: parts[ks] = Z(64xK) * (X-mu)(64xK)^T, dbuf pipeline ----
__global__ __launch_bounds__(256) void covk(const float* __restrict__ Z,
                                            const float* __restrict__ X,
                                            const float* __restrict__ mu,
                                            float* __restrict__ parts) {
    __shared__ float Zl[2][64 * 36];
    __shared__ float Xl[2][64 * 36];
    int bid = blockIdx.x;                 // 256 flat; ks fastest -> same-ks on one XCD
    int ks = bid & 15, it = (bid >> 4) & 3, jt = bid >> 6;
    int i0 = it * 64, j0 = jt * 64;
    int tid = threadIdx.x;
    int srow = tid >> 2, sq = tid & 3;
    const float* Zg = Z + (size_t)(i0 + srow) * D_DIM + sq * 8;
    const float* Xg = X + (size_t)(j0 + srow) * D_DIM + sq * 8;
    float muJ = mu[j0 + srow];
    int swoff = srow * 36 + sq * 8;
    int ti = tid >> 4, tj = tid & 15;

    float4 z0, z1, x0, x1;
    auto loadT = [&](int kc) {
        int k0 = ks * 512 + kc * 32;
        z0 = *(const float4*)(Zg + k0); z1 = *(const float4*)(Zg + k0 + 4);
        x0 = *(const float4*)(Xg + k0); x1 = *(const float4*)(Xg + k0 + 4);
    };
    auto writeT = [&](int pb) {
        *(float4*)(Zl[pb] + swoff)     = z0;
        *(float4*)(Zl[pb] + swoff + 4) = z1;
        *(float4*)(Xl[pb] + swoff)     = make_float4(x0.x - muJ, x0.y - muJ, x0.z - muJ, x0.w - muJ);
        *(float4*)(Xl[pb] + swoff + 4) = make_float4(x1.x - muJ, x1.y - muJ, x1.z - muJ, x1.w - muJ);
    };

    float acc[4][4] = {};
    loadT(0); writeT(0); loadT(1);
    __syncthreads();
    for (int kc = 0; kc < 16; ++kc) {
        int pb = kc & 1;
        if (kc + 1 < 16) writeT(pb ^ 1);
        if (kc + 2 < 16) loadT(kc + 2);
        #pragma unroll
        for (int k4 = 0; k4 < 8; ++k4) {
            float4 za[4], xb[4];
            #pragma unroll
            for (int a = 0; a < 4; ++a) za[a] = *(const float4*)(Zl[pb] + (a * 16 + ti) * 36 + k4 * 4);
            #pragma unroll
            for (int b = 0; b < 4; ++b) xb[b] = *(const float4*)(Xl[pb] + (b * 16 + tj) * 36 + k4 * 4);
            #pragma unroll
            for (int a = 0; a < 4; ++a)
                #pragma unroll
                for (int b = 0; b < 4; ++b) {
                    acc[a][b] = fmaf(za[a].x, xb[b].x, acc[a][b]);
                    acc[a][b] = fmaf(za[a].y, xb[b].y, acc[a][b]);
                    acc[a][b] = fmaf(za[a].z, xb[b].z, acc[a][b]);
                    acc[a][b] = fmaf(za[a].w, xb[b].w, acc[a][b]);
                }
        }
        __syncthreads();
    }
    #pragma unroll
    for (int a = 0; a < 4; ++a)
        #pragma unroll
        for (int b = 0; b < 4; ++b)
            parts[(size_t)ks * 65536 + (size_t)(i0 + a * 16 + ti) * 256 + (j0 + b * 16 + tj)] = acc[a][b];
}

__global__ __launch_bounds__(256) void reduce_cov(const float* __restrict__ parts,
                                                  u16* __restrict__ out) {
    int idx = blockIdx.x * 256 + threadIdx.x;
    float s = 0.f;
    #pragma unroll
    for (int sl = 0; sl < 16; ++sl) s += parts[(size_t)sl * 65536 + idx];
    out[idx] = f2bf(s);
}

// ---------------- bf16 MFMA GEMM, dbuf 1-barrier pipeline ----------------------
// BM=256/block-col, BN in {64,128}, BK=32, 512 thr (8 waves 4x2), KS k-slices
// MODE 0: fp32 partials; MODE 1: bf16 out; MODE 2: fp32 out. AF32: A is fp32.
template<int MODE, int AF32, int BN, int KS>
__global__ __launch_bounds__(512) void gemm_nn(const void* __restrict__ Avoid, int lda,
                                               const float* __restrict__ B, int ldb,
                                               int N, int sliceLen,
                                               float* __restrict__ outF,
                                               u16* __restrict__ outB,
                                               int ldc, int partStride) {
    constexpr int NI  = BN / 32;   // n-frags per wave
    constexpr int NPT = BN / 16;   // B elements staged per thread
    __shared__ u16 Alds[2][256 * 32];
    __shared__ u16 Blds[2][BN * 32];
    const int tid = threadIdx.x;
    const int bid = blockIdx.x;
    const int ks  = bid % KS;              // ks fastest -> same-ks blocks on one XCD
    const int nb  = (bid / KS) * BN;
    const int mt  = blockIdx.y;
    const int k0base = ks * sliceLen;
    const int ksteps = sliceLen >> 5;
    const int lane = tid & 63, wv = tid >> 6;
    const int wm = wv >> 1, wn = wv & 1;

    // A staging: thread covers 16 elements of one row
    const int sArow = tid >> 1, sAe = (tid & 1) * 16;
    const u16*   ApB = (const u16*)Avoid   + (size_t)(mt * 256 + sArow) * lda + sAe + k0base;
    const float* ApF = (const float*)Avoid + (size_t)(mt * 256 + sArow) * lda + sAe + k0base;
    const int aw0 = swz(sArow, sAe >> 3);
    const int aw1 = swz(sArow, (sAe >> 3) + 1);
    // B staging: thread covers NPT fp32 of one k-row
    const int sBk = tid >> 4, sBn = (tid & 15) * NPT;
    const float* Bp = B + (size_t)(k0base + sBk) * ldb + nb + sBn;
    int bw[NPT];
    #pragma unroll
    for (int j = 0; j < NPT; ++j) bw[j] = swz(sBn + j, sBk >> 3) + (sBk & 7) * 2;
    // fragment read offsets
    const int kg = lane >> 4, l15 = lane & 15;
    int aoff[4], boff[NI];
    #pragma unroll
    for (int mi = 0; mi < 4; ++mi) { int r = wm * 64 + mi * 16 + l15; aoff[mi] = swz(r, kg); }
    #pragma unroll
    for (int ni = 0; ni < NI; ++ni) { int r = wn * (BN / 2) + ni * 16 + l15; boff[ni] = swz(r, kg); }

    int4 av0, av1;
    float4 fa0, fa1, fa2, fa3;
    float4 bvv[NPT / 4];

    auto loadT = [&](int kt) {
        if constexpr (AF32) {
            const float* ap = ApF + (kt << 5);
            fa0 = *(const float4*)(ap);     fa1 = *(const float4*)(ap + 4);
            fa2 = *(const float4*)(ap + 8); fa3 = *(const float4*)(ap + 12);
        } else {
            const u16* ap = ApB + (kt << 5);
            av0 = *(const int4*)(ap);
            av1 = *(const int4*)(ap + 8);
        }
        const float* bp = Bp + (size_t)(kt << 5) * ldb;
        #pragma unroll
        for (int j = 0; j < NPT / 4; ++j) bvv[j] = *(const float4*)(bp + j * 4);
    };
    auto writeT = [&](int pb) {
        int4 w0, w1;
        if constexpr (AF32) {
            w0.x = (int)((u32)f2bf(fa0.x) | ((u32)f2bf(fa0.y) << 16));
            w0.y = (int)((u32)f2bf(fa0.z) | ((u32)f2bf(fa0.w) << 16));
            w0.z = (int)((u32)f2bf(fa1.x) | ((u32)f2bf(fa1.y) << 16));
            w0.w = (int)((u32)f2bf(fa1.z) | ((u32)f2bf(fa1.w) << 16));
            w1.x = (int)((u32)f2bf(fa2.x) | ((u32)f2bf(fa2.y) << 16));
            w1.y = (int)((u32)f2bf(fa2.z) | ((u32)f2bf(fa2.w) << 16));
            w1.z = (int)((u32)f2bf(fa3.x) | ((u32)f2bf(fa3.y) << 16));
            w1.w = (int)((u32)f2bf(fa3.z) | ((u32)f2bf(fa3.w) << 16));
        } else { w0 = av0; w1 = av1; }
        char* AB = (char*)Alds[pb];
        char* BB = (char*)Blds[pb];
        *(int4*)(AB + aw0) = w0;
        *(int4*)(AB + aw1) = w1;
        #pragma unroll
        for (int j = 0; j < NPT; ++j) {
            float bj = ((const float*)bvv)[j];
            *(u16*)(BB + bw[j]) = f2bf(bj);
        }
    };

    f32x4 acc[4][NI];
    #pragma unroll
    for (int mi = 0; mi < 4; ++mi)
        #pragma unroll
        for (int ni = 0; ni < NI; ++ni) { f32x4 zz = {0.f, 0.f, 0.f, 0.f}; acc[mi][ni] = zz; }

    loadT(0); writeT(0); loadT(1);
    __syncthreads();
    for (int kt = 0; kt < ksteps; ++kt) {
        const int pb = kt & 1;
        if (kt + 1 < ksteps) writeT(pb ^ 1);
        if (kt + 2 < ksteps) loadT(kt + 2);
        const char* AB = (const char*)Alds[pb];
        const char* BB = (const char*)Blds[pb];
        bf16x8 af[4], bfr[NI];
        #pragma unroll
        for (int mi = 0; mi < 4; ++mi) af[mi] = *(const bf16x8*)(AB + aoff[mi]);
        #pragma unroll
        for (int ni = 0; ni < NI; ++ni) bfr[ni] = *(const bf16x8*)(BB + boff[ni]);
        #pragma unroll
        for (int mi = 0; mi < 4; ++mi)
            #pragma unroll
            for (int ni = 0; ni < NI; ++ni)
                acc[mi][ni] = __builtin_amdgcn_mfma_f32_16x16x32_bf16(af[mi], bfr[ni], acc[mi][ni], 0, 0, 0);
        __syncthreads();
    }
    // epilogue: C/D layout col=lane&15, row=(lane>>4)*4+reg
    const int rq = lane >> 4;
    #pragma unroll
    for (int mi = 0; mi < 4; ++mi)
        #pragma unroll
        for (int ni = 0; ni < NI; ++ni)
            #pragma unroll
            for (int r = 0; r < 4; ++r) {
                int m = wm * 64 + mi * 16 + rq * 4 + r;
                int n = nb + wn * (BN / 2) + ni * 16 + l15;
                float v = acc[mi][ni][r];
                if (MODE == 0)
                    outF[(size_t)ks * partStride + (size_t)m * N + n] = v;
                else if (MODE == 1)
                    outB[(size_t)(mt * 256 + m) * ldc + n] = f2bf(v);
                else
                    outF[(size_t)(mt * 256 + m) * ldc + n] = v;
            }
}

// ---------------- reduce split-K partials (+bias+GELU) -------------------------
__global__ __launch_bounds__(256) void reduce_fc(const float* __restrict__ parts,
                                                 int MN, int N,
                                                 const float* __restrict__ bias,
                                                 u16* __restrict__ outB,
                                                 float* __restrict__ outF) {
    int i4 = (blockIdx.x * 256 + threadIdx.x) * 4;
    if (i4 >= MN) return;
    float4 s = *(const float4*)(parts + i4);
    #pragma unroll
    for (int sl = 1; sl < 8; ++sl) {
        float4 p = *(const float4*)(parts + (size_t)sl * MN + i4);
        s.x += p.x; s.y += p.y; s.z += p.z; s.w += p.w;
    }
    int col = i4 & (N - 1);
    float4 b = *(const float4*)(bias + col);
    s.x = geluf(s.x + b.x); s.y = geluf(s.y + b.y);
    s.z = geluf(s.z + b.z); s.w = geluf(s.w + b.w);
    if (outB) {
        uint2 pk;
        pk.x = (u32)f2bf(s.x) | ((u32)f2bf(s.y) << 16);
        pk.y = (u32)f2bf(s.z) | ((u32)f2bf(s.w) << 16);
        *(uint2*)(outB + i4) = pk;
    }
    if (outF) *(float4*)(outF + i4) = s;
}

extern "C" void kernel_launch(void* const* d_in, const int* in_sizes, int n_in,
                              void* d_out, int out_size, void* d_ws, size_t ws_size,
                              hipStream_t stream) {
    const float* X     = (const float*)d_in[0];
    const float* wn_w1 = (const float*)d_in[1];
    const float* wn_b1 = (const float*)d_in[2];
    const float* wn_w2 = (const float*)d_in[3];
    const float* wn_b2 = (const float*)d_in[4];
    const float* fc1_w = (const float*)d_in[5];
    const float* fc1_b = (const float*)d_in[6];
    const float* fc2_w = (const float*)d_in[7];
    const float* fc2_b = (const float*)d_in[8];
    const float* proj  = (const float*)d_in[9];

    char* ws = (char*)d_ws;
    size_t off = 0;
    auto alloc = [&](size_t bytes) { size_t o = off; off += (bytes + 255) & ~(size_t)255; return o; };
    float* c_ws   = (float*)(ws + alloc(64 * 4));
    float* mu_ws  = (float*)(ws + alloc(C_DIM * 4));
    float* Zf     = (float*)(ws + alloc((size_t)C_DIM * D_DIM * 4));
    u16*   comb   = (u16*)  (ws + alloc((size_t)C_DIM * TWO_D * 2));
    float* covp   = (float*)(ws + alloc((size_t)16 * 65536 * 4));
    u16*   covbf  = (u16*)  (ws + alloc((size_t)65536 * 2));
    float* p1     = (float*)(ws + alloc((size_t)8 * C_DIM * HIDD * 4));
    u16*   hbf    = (u16*)  (ws + alloc((size_t)C_DIM * HIDD * 2));
    float* p2     = (float*)(ws + alloc((size_t)8 * C_DIM * Y1D * 4));
    float* of32   = (float*)(ws + alloc((size_t)C_DIM * Y1D * 4));

    wcoef<<<1, 256, 0, stream>>>(wn_w1, wn_b1, wn_w2, wn_b2, c_ws);
    filterk<<<C_DIM, 256, 0, stream>>>(X, c_ws, mu_ws, Zf, comb);
    covk<<<256, 256, 0, stream>>>(Zf, X, mu_ws, covp);
    reduce_cov<<<256, 256, 0, stream>>>(covp, covbf);
    // cov_interaction = cov @ X  -> bf16 right half of combined
    gemm_nn<1, 0, 64, 1><<<dim3(D_DIM / 64, 1, 1), 512, 0, stream>>>(covbf, C_DIM, X, D_DIM,
        D_DIM, C_DIM, nullptr, comb + D_DIM, TWO_D, 0);
    // fc1: combined @ fc1_w, BN=128 (halves A re-reads), 8 K-slices XCD-clustered
    gemm_nn<0, 0, 128, 8><<<dim3((HIDD / 128) * 8, 1, 1), 512, 0, stream>>>(comb, TWO_D, fc1_w, HIDD,
        HIDD, TWO_D / 8, p1, nullptr, 0, C_DIM * HIDD);
    reduce_fc<<<(C_DIM * HIDD / 4 + 255) / 256, 256, 0, stream>>>(p1, C_DIM * HIDD, HIDD, fc1_b, hbf, nullptr);
    // fc2: h @ fc2_w
    gemm_nn<0, 0, 64, 8><<<dim3((Y1D / 64) * 8, 1, 1), 512, 0, stream>>>(hbf, HIDD, fc2_w, Y1D,
        Y1D, HIDD / 8, p2, nullptr, 0, C_DIM * Y1D);
    reduce_fc<<<(C_DIM * Y1D / 4 + 255) / 256, 256, 0, stream>>>(p2, C_DIM * Y1D, Y1D, fc2_b, nullptr, of32);
    // out = proj @ o   (A fp32 staged-converted; M=512 -> 2 m-tiles)
    gemm_nn<2, 1, 64, 1><<<dim3(Y1D / 64, 2, 1), 512, 0, stream>>>(proj, C_DIM, of32, Y1D,
        Y1D, C_DIM, (float*)d_out, nullptr, Y1D, 0);
}

// Round 5
// 203.652 us; speedup vs baseline: 1.1487x; 1.1487x over previous
//
#include <hip/hip_runtime.h>
#include <math.h>

typedef unsigned short u16;
typedef unsigned int   u32;

typedef __bf16 bf16x8 __attribute__((ext_vector_type(8)));
typedef float  f32x4  __attribute__((ext_vector_type(4)));

#define C_DIM 256
#define D_DIM 8192
#define QQ    32
#define HIDD  4096
#define Y0D   512
#define Y1D   2048
#define TWO_D 16384

__device__ __forceinline__ u16 f2bf(float f) {
    union { float f; u32 u; } v; v.f = f;
    u32 r = v.u + 0x7fffu + ((v.u >> 16) & 1u);   // RNE
    return (u16)(r >> 16);
}
__device__ __forceinline__ float geluf(float x) {
    return 0.5f * x * (1.0f + erff(x * 0.70710678118654752f));
}
// LDS swizzle: 16B chunk kg within a 64B row, XOR'd by row bits -> <=2-way conflicts
__device__ __forceinline__ int swz(int row, int kg) {
    return row * 64 + (((kg) ^ ((row >> 1) & 3)) << 4);
}
// fp32 LDS swizzle for the filter row buffer
__device__ __forceinline__ int xsw(int t) {
    int ch = t >> 2;
    return (((ch ^ ((ch >> 3) & 7))) << 2) | (t & 3);
}

// ---- per-row: weight-net coefs (fused), mean -> mu[], Z = FIR(c, X-mu), bf16(X) ----
__global__ __launch_bounds__(256) void filterk(const float* __restrict__ X,
                                               const float* __restrict__ w1,
                                               const float* __restrict__ b1,
                                               const float* __restrict__ w2,
                                               const float* __restrict__ b2,
                                               float* __restrict__ mu_out,
                                               float* __restrict__ Z,
                                               u16* __restrict__ comb) {
    __shared__ float Xl[8240];
    __shared__ float wl[65];
    __shared__ float cl[40];
    __shared__ float red[4];
    int i = blockIdx.x, tid = threadIdx.x;
    int lane = tid & 63, wv = tid >> 6;
    const float* row = X + (size_t)i * D_DIM;
    float s = 0.f;
    #pragma unroll
    for (int q = 0; q < 8; ++q) {
        int t = tid * 32 + q * 4;
        float4 v = *(const float4*)(row + t);
        s += v.x + v.y + v.z + v.w;
        *(float4*)(Xl + xsw(t)) = v;
    }
    // weight network, recomputed per block (cheap; saves a launch)
    float w1l = w1[lane], b1l = b1[lane], w2l = w2[lane], b2l = b2[0];
    for (int li = wv; li < 65; li += 4) {
        float lag = (float)(li - 32);
        float h = geluf(lag * w1l + b1l);
        float p = h * w2l;
        #pragma unroll
        for (int off = 32; off; off >>= 1) p += __shfl_xor(p, off);
        if (lane == 0) wl[li] = p + b2l;
    }
    #pragma unroll
    for (int off = 32; off; off >>= 1) s += __shfl_xor(s, off);
    if (lane == 0) red[wv] = s;
    __syncthreads();
    if (tid <= 32) {
        cl[tid] = (tid == 0) ? wl[32] / (float)D_DIM
                             : (wl[32 - tid] + wl[32 + tid]) / ((float)D_DIM - (float)tid);
    }
    if (tid == 33) {
        float ssum = wl[32] / (float)D_DIM;
        for (int k = 1; k <= 32; ++k) ssum += (wl[32 - k] + wl[32 + k]) / ((float)D_DIM - (float)k);
        cl[33] = ssum;
    }
    float mu = (red[0] + red[1] + red[2] + red[3]) * (1.f / (float)D_DIM);
    if (tid == 0) mu_out[i] = mu;
    if (tid < 10) {  // pad window with mu => (pad - mu) contributes 0 == truncation
        float4 mv = make_float4(mu, mu, mu, mu);
        *(float4*)(Xl + xsw(D_DIM + tid * 4)) = mv;
    }
    __syncthreads();
    float csum = cl[33];
    #pragma unroll
    for (int ch = 0; ch < 8; ++ch) {
        int t4 = tid * 32 + ch * 4;
        float w[40] __attribute__((aligned(16)));
        #pragma unroll
        for (int g = 0; g < 10; ++g)
            *(float4*)(w + g * 4) = *(const float4*)(Xl + xsw(t4 + g * 4));
        float za[4]; u16 cb[4];
        #pragma unroll
        for (int j = 0; j < 4; ++j) {
            float a = 0.f;
            #pragma unroll
            for (int k = 0; k < 33; ++k) a = fmaf(cl[k], w[j + k], a);
            za[j] = a - mu * csum;     // == sum_k c_k*(x[t+k]-mu) over valid k
            cb[j] = f2bf(w[j]);        // combined left half = bf16(X)
        }
        *(float4*)(Z + (size_t)i * D_DIM + t4) = make_float4(za[0], za[1], za[2], za[3]);
        uint2 pk; pk.x = (u32)cb[0] | ((u32)cb[1] << 16); pk.y = (u32)cb[2] | ((u32)cb[3] << 16);
        *(uint2*)(comb + (size_t)i * TWO_D + t4) = pk;
    }
}

// -------- cov partials: parts[ks] = Z(64xK) * (X-mu)(64xK)^T, dbuf pipeline ----
__global__ __launch_bounds__(256) void covk(const float* __restrict__ Z,
                                            const float* __restrict__ X,
                                            const float* __restrict__ mu,
                                            float* __restrict__ parts) {
    __shared__ float Zl[2][64 * 36];
    __shared__ float Xl[2][64 * 36];
    int bid = blockIdx.x;                 // 256 flat; ks fastest -> same-ks on one XCD
    int ks = bid & 15, it = (bid >> 4) & 3, jt = bid >> 6;
    int i0 = it * 64, j0 = jt * 64;
    int tid = threadIdx.x;
    int srow = tid >> 2, sq = tid & 3;
    const float* Zg = Z + (size_t)(i0 + srow) * D_DIM + sq * 8;
    const float* Xg = X + (size_t)(j0 + srow) * D_DIM + sq * 8;
    float muJ = mu[j0 + srow];
    int swoff = srow * 36 + sq * 8;
    int ti = tid >> 4, tj = tid & 15;

    float4 z0, z1, x0, x1;
    auto loadT = [&](int kc) {
        int k0 = ks * 512 + kc * 32;
        z0 = *(const float4*)(Zg + k0); z1 = *(const float4*)(Zg + k0 + 4);
        x0 = *(const float4*)(Xg + k0); x1 = *(const float4*)(Xg + k0 + 4);
    };
    auto writeT = [&](int pb) {
        *(float4*)(Zl[pb] + swoff)     = z0;
        *(float4*)(Zl[pb] + swoff + 4) = z1;
        *(float4*)(Xl[pb] + swoff)     = make_float4(x0.x - muJ, x0.y - muJ, x0.z - muJ, x0.w - muJ);
        *(float4*)(Xl[pb] + swoff + 4) = make_float4(x1.x - muJ, x1.y - muJ, x1.z - muJ, x1.w - muJ);
    };

    float acc[4][4] = {};
    loadT(0); writeT(0); loadT(1);
    __syncthreads();
    for (int kc = 0; kc < 16; ++kc) {
        int pb = kc & 1;
        if (kc + 1 < 16) writeT(pb ^ 1);
        if (kc + 2 < 16) loadT(kc + 2);
        #pragma unroll
        for (int k4 = 0; k4 < 8; ++k4) {
            float4 za[4], xb[4];
            #pragma unroll
            for (int a = 0; a < 4; ++a) za[a] = *(const float4*)(Zl[pb] + (a * 16 + ti) * 36 + k4 * 4);
            #pragma unroll
            for (int b = 0; b < 4; ++b) xb[b] = *(const float4*)(Xl[pb] + (b * 16 + tj) * 36 + k4 * 4);
            #pragma unroll
            for (int a = 0; a < 4; ++a)
                #pragma unroll
                for (int b = 0; b < 4; ++b) {
                    acc[a][b] = fmaf(za[a].x, xb[b].x, acc[a][b]);
                    acc[a][b] = fmaf(za[a].y, xb[b].y, acc[a][b]);
                    acc[a][b] = fmaf(za[a].z, xb[b].z, acc[a][b]);
                    acc[a][b] = fmaf(za[a].w, xb[b].w, acc[a][b]);
                }
        }
        __syncthreads();
    }
    #pragma unroll
    for (int a = 0; a < 4; ++a)
        #pragma unroll
        for (int b = 0; b < 4; ++b)
            parts[(size_t)ks * 65536 + (size_t)(i0 + a * 16 + ti) * 256 + (j0 + b * 16 + tj)] = acc[a][b];
}

__global__ __launch_bounds__(256) void reduce_cov(const float* __restrict__ parts,
                                                  u16* __restrict__ out) {
    int idx = blockIdx.x * 256 + threadIdx.x;
    float s = 0.f;
    #pragma unroll
    for (int sl = 0; sl < 16; ++sl) s += parts[(size_t)sl * 65536 + idx];
    out[idx] = f2bf(s);
}

// ---------------- bf16 MFMA GEMM, dbuf 1-barrier pipeline ----------------------
// BM=256/block-col, BN in {64,128}, BK=32, 512 thr (8 waves 4x2), KS k-slices
// MODE 0: bf16 partials; MODE 1: bf16 out; MODE 2: fp32 out. AF32: A is fp32.
template<int MODE, int AF32, int BN, int KS>
__global__ __launch_bounds__(512) void gemm_nn(const void* __restrict__ Avoid, int lda,
                                               const float* __restrict__ B, int ldb,
                                               int N, int sliceLen,
                                               float* __restrict__ outF,
                                               u16* __restrict__ outB,
                                               int ldc, int partStride) {
    constexpr int NI  = BN / 32;   // n-frags per wave
    constexpr int NPT = BN / 16;   // B elements staged per thread
    __shared__ u16 Alds[2][256 * 32];
    __shared__ u16 Blds[2][BN * 32];
    const int tid = threadIdx.x;
    const int bid = blockIdx.x;
    const int ks  = bid % KS;              // ks fastest -> same-ks blocks on one XCD
    const int nb  = (bid / KS) * BN;
    const int mt  = blockIdx.y;
    const int k0base = ks * sliceLen;
    const int ksteps = sliceLen >> 5;
    const int lane = tid & 63, wv = tid >> 6;
    const int wm = wv >> 1, wn = wv & 1;

    // A staging: thread covers 16 elements of one row
    const int sArow = tid >> 1, sAe = (tid & 1) * 16;
    const u16*   ApB = (const u16*)Avoid   + (size_t)(mt * 256 + sArow) * lda + sAe + k0base;
    const float* ApF = (const float*)Avoid + (size_t)(mt * 256 + sArow) * lda + sAe + k0base;
    const int aw0 = swz(sArow, sAe >> 3);
    const int aw1 = swz(sArow, (sAe >> 3) + 1);
    // B staging: thread covers NPT fp32 of one k-row
    const int sBk = tid >> 4, sBn = (tid & 15) * NPT;
    const float* Bp = B + (size_t)(k0base + sBk) * ldb + nb + sBn;
    int bw[NPT];
    #pragma unroll
    for (int j = 0; j < NPT; ++j) bw[j] = swz(sBn + j, sBk >> 3) + (sBk & 7) * 2;
    // fragment read offsets
    const int kg = lane >> 4, l15 = lane & 15;
    int aoff[4], boff[NI];
    #pragma unroll
    for (int mi = 0; mi < 4; ++mi) { int r = wm * 64 + mi * 16 + l15; aoff[mi] = swz(r, kg); }
    #pragma unroll
    for (int ni = 0; ni < NI; ++ni) { int r = wn * (BN / 2) + ni * 16 + l15; boff[ni] = swz(r, kg); }

    int4 av0, av1;
    float4 fa0, fa1, fa2, fa3;
    float4 bvv[NPT / 4];

    auto loadT = [&](int kt) {
        if constexpr (AF32) {
            const float* ap = ApF + (kt << 5);
            fa0 = *(const float4*)(ap);     fa1 = *(const float4*)(ap + 4);
            fa2 = *(const float4*)(ap + 8); fa3 = *(const float4*)(ap + 12);
        } else {
            const u16* ap = ApB + (kt << 5);
            av0 = *(const int4*)(ap);
            av1 = *(const int4*)(ap + 8);
        }
        const float* bp = Bp + (size_t)(kt << 5) * ldb;
        #pragma unroll
        for (int j = 0; j < NPT / 4; ++j) bvv[j] = *(const float4*)(bp + j * 4);
    };
    auto writeT = [&](int pb) {
        int4 w0, w1;
        if constexpr (AF32) {
            w0.x = (int)((u32)f2bf(fa0.x) | ((u32)f2bf(fa0.y) << 16));
            w0.y = (int)((u32)f2bf(fa0.z) | ((u32)f2bf(fa0.w) << 16));
            w0.z = (int)((u32)f2bf(fa1.x) | ((u32)f2bf(fa1.y) << 16));
            w0.w = (int)((u32)f2bf(fa1.z) | ((u32)f2bf(fa1.w) << 16));
            w1.x = (int)((u32)f2bf(fa2.x) | ((u32)f2bf(fa2.y) << 16));
            w1.y = (int)((u32)f2bf(fa2.z) | ((u32)f2bf(fa2.w) << 16));
            w1.z = (int)((u32)f2bf(fa3.x) | ((u32)f2bf(fa3.y) << 16));
            w1.w = (int)((u32)f2bf(fa3.z) | ((u32)f2bf(fa3.w) << 16));
        } else { w0 = av0; w1 = av1; }
        char* AB = (char*)Alds[pb];
        char* BB = (char*)Blds[pb];
        *(int4*)(AB + aw0) = w0;
        *(int4*)(AB + aw1) = w1;
        #pragma unroll
        for (int j = 0; j < NPT; ++j) {
            float bj = ((const float*)bvv)[j];
            *(u16*)(BB + bw[j]) = f2bf(bj);
        }
    };

    f32x4 acc[4][NI];
    #pragma unroll
    for (int mi = 0; mi < 4; ++mi)
        #pragma unroll
        for (int ni = 0; ni < NI; ++ni) { f32x4 zz = {0.f, 0.f, 0.f, 0.f}; acc[mi][ni] = zz; }

    loadT(0); writeT(0); loadT(1);
    __syncthreads();
    for (int kt = 0; kt < ksteps; ++kt) {
        const int pb = kt & 1;
        if (kt + 1 < ksteps) writeT(pb ^ 1);
        if (kt + 2 < ksteps) loadT(kt + 2);
        const char* AB = (const char*)Alds[pb];
        const char* BB = (const char*)Blds[pb];
        bf16x8 af[4], bfr[NI];
        #pragma unroll
        for (int mi = 0; mi < 4; ++mi) af[mi] = *(const bf16x8*)(AB + aoff[mi]);
        #pragma unroll
        for (int ni = 0; ni < NI; ++ni) bfr[ni] = *(const bf16x8*)(BB + boff[ni]);
        #pragma unroll
        for (int mi = 0; mi < 4; ++mi)
            #pragma unroll
            for (int ni = 0; ni < NI; ++ni)
                acc[mi][ni] = __builtin_amdgcn_mfma_f32_16x16x32_bf16(af[mi], bfr[ni], acc[mi][ni], 0, 0, 0);
        __syncthreads();
    }
    // epilogue: C/D layout col=lane&15, row=(lane>>4)*4+reg
    const int rq = lane >> 4;
    #pragma unroll
    for (int mi = 0; mi < 4; ++mi)
        #pragma unroll
        for (int ni = 0; ni < NI; ++ni)
            #pragma unroll
            for (int r = 0; r < 4; ++r) {
                int m = wm * 64 + mi * 16 + rq * 4 + r;
                int n = nb + wn * (BN / 2) + ni * 16 + l15;
                float v = acc[mi][ni][r];
                if (MODE == 0)
                    outB[(size_t)ks * partStride + (size_t)m * N + n] = f2bf(v);
                else if (MODE == 1)
                    outB[(size_t)(mt * 256 + m) * ldc + n] = f2bf(v);
                else
                    outF[(size_t)(mt * 256 + m) * ldc + n] = v;
            }
}

// -------- reduce split-K bf16 partials (+bias+GELU), 8 elems/thread ------------
__global__ __launch_bounds__(256) void reduce_fc(const u16* __restrict__ parts,
                                                 int MN, int Nmask,
                                                 const float* __restrict__ bias,
                                                 u16* __restrict__ outB,
                                                 float* __restrict__ outF) {
    int i8 = (blockIdx.x * 256 + threadIdx.x) * 8;
    if (i8 >= MN) return;
    float s[8] = {};
    #pragma unroll
    for (int sl = 0; sl < 8; ++sl) {
        uint4 v = *(const uint4*)(parts + (size_t)sl * MN + i8);
        u32 w[4] = {v.x, v.y, v.z, v.w};
        #pragma unroll
        for (int j = 0; j < 4; ++j) {
            union { u32 u; float f; } lo, hi;
            lo.u = (w[j] & 0xffffu) << 16; hi.u = w[j] & 0xffff0000u;
            s[2 * j]     += lo.f;
            s[2 * j + 1] += hi.f;
        }
    }
    int col = i8 & Nmask;
    float4 b0 = *(const float4*)(bias + col);
    float4 b1 = *(const float4*)(bias + col + 4);
    s[0] = geluf(s[0] + b0.x); s[1] = geluf(s[1] + b0.y);
    s[2] = geluf(s[2] + b0.z); s[3] = geluf(s[3] + b0.w);
    s[4] = geluf(s[4] + b1.x); s[5] = geluf(s[5] + b1.y);
    s[6] = geluf(s[6] + b1.z); s[7] = geluf(s[7] + b1.w);
    if (outB) {
        uint4 pk;
        pk.x = (u32)f2bf(s[0]) | ((u32)f2bf(s[1]) << 16);
        pk.y = (u32)f2bf(s[2]) | ((u32)f2bf(s[3]) << 16);
        pk.z = (u32)f2bf(s[4]) | ((u32)f2bf(s[5]) << 16);
        pk.w = (u32)f2bf(s[6]) | ((u32)f2bf(s[7]) << 16);
        *(uint4*)(outB + i8) = pk;
    }
    if (outF) {
        *(float4*)(outF + i8)     = make_float4(s[0], s[1], s[2], s[3]);
        *(float4*)(outF + i8 + 4) = make_float4(s[4], s[5], s[6], s[7]);
    }
}

extern "C" void kernel_launch(void* const* d_in, const int* in_sizes, int n_in,
                              void* d_out, int out_size, void* d_ws, size_t ws_size,
                              hipStream_t stream) {
    const float* X     = (const float*)d_in[0];
    const float* wn_w1 = (const float*)d_in[1];
    const float* wn_b1 = (const float*)d_in[2];
    const float* wn_w2 = (const float*)d_in[3];
    const float* wn_b2 = (const float*)d_in[4];
    const float* fc1_w = (const float*)d_in[5];
    const float* fc1_b = (const float*)d_in[6];
    const float* fc2_w = (const float*)d_in[7];
    const float* fc2_b = (const float*)d_in[8];
    const float* proj  = (const float*)d_in[9];

    char* ws = (char*)d_ws;
    size_t off = 0;
    auto alloc = [&](size_t bytes) { size_t o = off; off += (bytes + 255) & ~(size_t)255; return o; };
    float* mu_ws  = (float*)(ws + alloc(C_DIM * 4));
    float* Zf     = (float*)(ws + alloc((size_t)C_DIM * D_DIM * 4));
    u16*   comb   = (u16*)  (ws + alloc((size_t)C_DIM * TWO_D * 2));
    float* covp   = (float*)(ws + alloc((size_t)16 * 65536 * 4));
    u16*   covbf  = (u16*)  (ws + alloc((size_t)65536 * 2));
    u16*   p1b    = (u16*)  (ws + alloc((size_t)8 * C_DIM * HIDD * 2));
    u16*   hbf    = (u16*)  (ws + alloc((size_t)C_DIM * HIDD * 2));
    u16*   p2b    = (u16*)  (ws + alloc((size_t)8 * C_DIM * Y1D * 2));
    float* of32   = (float*)(ws + alloc((size_t)C_DIM * Y1D * 4));

    filterk<<<C_DIM, 256, 0, stream>>>(X, wn_w1, wn_b1, wn_w2, wn_b2, mu_ws, Zf, comb);
    covk<<<256, 256, 0, stream>>>(Zf, X, mu_ws, covp);
    reduce_cov<<<256, 256, 0, stream>>>(covp, covbf);
    // cov_interaction = cov @ X  -> bf16 right half of combined
    gemm_nn<1, 0, 64, 1><<<dim3(D_DIM / 64, 1, 1), 512, 0, stream>>>(covbf, C_DIM, X, D_DIM,
        D_DIM, C_DIM, nullptr, comb + D_DIM, TWO_D, 0);
    // fc1: combined @ fc1_w, BN=64/KS=8 -> 512 blocks (2/CU), bf16 partials
    gemm_nn<0, 0, 64, 8><<<dim3((HIDD / 64) * 8, 1, 1), 512, 0, stream>>>(comb, TWO_D, fc1_w, HIDD,
        HIDD, TWO_D / 8, nullptr, p1b, 0, C_DIM * HIDD);
    reduce_fc<<<(C_DIM * HIDD / 8 + 255) / 256, 256, 0, stream>>>(p1b, C_DIM * HIDD, HIDD - 1, fc1_b, hbf, nullptr);
    // fc2: h @ fc2_w, bf16 partials
    gemm_nn<0, 0, 64, 8><<<dim3((Y1D / 64) * 8, 1, 1), 512, 0, stream>>>(hbf, HIDD, fc2_w, Y1D,
        Y1D, HIDD / 8, nullptr, p2b, 0, C_DIM * Y1D);
    reduce_fc<<<(C_DIM * Y1D / 8 + 255) / 256, 256, 0, stream>>>(p2b, C_DIM * Y1D, Y1D - 1, fc2_b, nullptr, of32);
    // out = proj @ o   (A fp32 staged-converted; M=512 -> 2 m-tiles)
    gemm_nn<2, 1, 64, 1><<<dim3(Y1D / 64, 2, 1), 512, 0, stream>>>(proj, C_DIM, of32, Y1D,
        Y1D, C_DIM, (float*)d_out, nullptr, Y1D, 0);
}